// Round 4
// baseline (106.778 us; speedup 1.0000x reference)
//
#include <hip/hip_runtime.h>

#define DD 48
#define HH 256
#define WW 256
#define HM 128
#define WM 128
#define NPH 4
#define PLANE (DD * HH * WW)      // 3145728
#define MPLANE (DD * HM * WM)     // 786432

// One thread per (z,y,x). Phase-0 copy + 4 warped phases.
// sched_barrier(0) fences force all loads of a stage to issue before any
// consumer, so the wave pays gather latency once (true MLP), not 8-16x.
__global__ __launch_bounds__(256, 4) void mvf_warp_fused(
    const float* __restrict__ img,   // [48,256,256,2]
    const float* __restrict__ mvf,   // [4,3,48,128,128]
    float* __restrict__ out)         // [5,48,256,256,2]
{
    // XCD-chunked: XCD k (= blockIdx%8) owns y-band [32k,32k+32), z swept slow.
    int b   = blockIdx.x;
    int xcd = b & 7;
    int c   = b >> 3;
    int z   = c >> 5;                // 0 .. 47
    int y   = (xcd << 5) | (c & 31); // 0 .. 255
    int x   = threadIdx.x;           // 0 .. 255

    const float2* img2 = (const float2*)img;
    float2* out2 = (float2*)out;
    int pidx = (z * HH + y) * WW + x;

    // ---- mvf bilinear weights (2x half-pixel upsample, clamped) ----
    float ys = fminf(fmaxf((float)y * 0.5f - 0.25f, 0.0f), (float)(HM - 1));
    float xs = fminf(fmaxf((float)x * 0.5f - 0.25f, 0.0f), (float)(WM - 1));
    int y0 = min((int)ys, HM - 2);
    int x0 = min((int)xs, WM - 2);
    float wy = ys - (float)y0;
    float wx = xs - (float)x0;
    float w00 = (1.0f - wy) * (1.0f - wx);
    float w01 = (1.0f - wy) * wx;
    float w10 = wy * (1.0f - wx);
    float w11 = wy * wx;
    int mbase = z * (HM * WM) + y0 * WM + x0;

    // ---- stage A: issue all 24 mvf loads + phase-0 image load ----
    float2 ma[12], mb[12];
#pragma unroll
    for (int i = 0; i < 12; ++i) {
        const float* m = mvf + i * MPLANE + mbase;
        ma[i] = *(const float2*)m;
        mb[i] = *(const float2*)(m + WM);
    }
    float2 self = img2[pidx];
    __builtin_amdgcn_sched_barrier(0);   // all stage-A loads issued above

    out2[pidx] = self;                   // phase-0 copy
    float mvv[NPH][3];
#pragma unroll
    for (int ph = 0; ph < NPH; ++ph)
#pragma unroll
        for (int ch = 0; ch < 3; ++ch) {
            int i = ph * 3 + ch;
            mvv[ph][ch] = w00 * ma[i].x + w01 * ma[i].y + w10 * mb[i].x + w11 * mb[i].y;
        }

    // ---- stage B: addresses + masked weights, then ALL 32 gather loads ----
    int   off[NPH][4];
    float s0[NPH], s1[NPH], t0[NPH], t1[NPH], sw0[NPH], sw1[NPH];
#pragma unroll
    for (int ph = 0; ph < NPH; ++ph) {
        float zc = (float)z + mvv[ph][0];
        float yc = (float)y + 2.0f * mvv[ph][1];
        float xc = (float)x + 2.0f * mvv[ph][2];
        float zf = floorf(zc), yf = floorf(yc), xf = floorf(xc);
        int zi = (int)zf, yi = (int)yf, xi = (int)xf;
        float wz = zc - zf, wyg = yc - yf, wxg = xc - xf;

        int zc0 = min(max(zi,     0), DD - 1);
        int zc1 = min(max(zi + 1, 0), DD - 1);
        int yc0 = min(max(yi,     0), HH - 1);
        int yc1 = min(max(yi + 1, 0), HH - 1);
        int xb  = min(max(xi,     0), WW - 2);

        s0[ph] = (zi     >= 0 && zi     < DD) ? (1.0f - wz)  : 0.0f;
        s1[ph] = (zi + 1 >= 0 && zi + 1 < DD) ? wz           : 0.0f;
        t0[ph] = (yi     >= 0 && yi     < HH) ? (1.0f - wyg) : 0.0f;
        t1[ph] = (yi + 1 >= 0 && yi + 1 < HH) ? wyg          : 0.0f;
        // loaded pair is (xb, xb+1); corner xi at slot d, xi+1 at d+1,
        // d = xi - xb in {-1,0,1}
        int d = xi - xb;
        sw0[ph] = (d == 0) ? (1.0f - wxg) : ((d == -1) ? wxg : 0.0f);
        sw1[ph] = (d == 0) ? wxg : ((d == 1) ? (1.0f - wxg) : 0.0f);

        off[ph][0] = (zc0 * HH + yc0) * WW + xb;
        off[ph][1] = (zc0 * HH + yc1) * WW + xb;
        off[ph][2] = (zc1 * HH + yc0) * WW + xb;
        off[ph][3] = (zc1 * HH + yc1) * WW + xb;
    }

    float2 lo[16], hi[16];
#pragma unroll
    for (int ph = 0; ph < NPH; ++ph)
#pragma unroll
        for (int k = 0; k < 4; ++k) {
            const float2* p = img2 + off[ph][k];
            lo[ph * 4 + k] = p[0];
            hi[ph * 4 + k] = p[1];
        }
    __builtin_amdgcn_sched_barrier(0);   // all 32 gathers issued above

    // ---- combine + store ----
#pragma unroll
    for (int ph = 0; ph < NPH; ++ph) {
        int i0 = ph * 4;
        float r0a = sw0[ph] * lo[i0+0].x + sw1[ph] * hi[i0+0].x;
        float r0b = sw0[ph] * lo[i0+0].y + sw1[ph] * hi[i0+0].y;
        float r1a = sw0[ph] * lo[i0+1].x + sw1[ph] * hi[i0+1].x;
        float r1b = sw0[ph] * lo[i0+1].y + sw1[ph] * hi[i0+1].y;
        float r2a = sw0[ph] * lo[i0+2].x + sw1[ph] * hi[i0+2].x;
        float r2b = sw0[ph] * lo[i0+2].y + sw1[ph] * hi[i0+2].y;
        float r3a = sw0[ph] * lo[i0+3].x + sw1[ph] * hi[i0+3].x;
        float r3b = sw0[ph] * lo[i0+3].y + sw1[ph] * hi[i0+3].y;
        float a0 = s0[ph] * (t0[ph] * r0a + t1[ph] * r1a)
                 + s1[ph] * (t0[ph] * r2a + t1[ph] * r3a);
        float a1 = s0[ph] * (t0[ph] * r0b + t1[ph] * r1b)
                 + s1[ph] * (t0[ph] * r2b + t1[ph] * r3b);
        out2[(ph + 1) * PLANE + pidx] = make_float2(a0, a1);
    }
}

extern "C" void kernel_launch(void* const* d_in, const int* in_sizes, int n_in,
                              void* d_out, int out_size, void* d_ws, size_t ws_size,
                              hipStream_t stream) {
    const float* img = (const float*)d_in[0];   // [1,1,48,256,256,2]
    const float* mvf = (const float*)d_in[1];   // [1,4,3,48,128,128]
    float* out = (float*)d_out;                 // [1,5,48,256,256,2]

    mvf_warp_fused<<<DD * HH, 256, 0, stream>>>(img, mvf, out);
}